// Round 1
// baseline (220.382 us; speedup 1.0000x reference)
//
#include <hip/hip_runtime.h>
#include <stdint.h>

typedef unsigned short u16;
typedef short bf16x8 __attribute__((ext_vector_type(8)));
typedef float f32x4 __attribute__((ext_vector_type(4)));

#define NIB 32
#define NOB 32
#define ABI 8
#define BSZ 128
#define INF 4096
#define OUTF 4096
#define LRK 64
#define NROWS 8192
#define KTOT 1088   // 8*128 sparse + 64 lowrank
#define BM 128
#define BN 128
#define BK 64
#define NKSTEP 17   // 1088/64

__device__ __forceinline__ u16 f2bf(float f) {
    uint32_t u = __float_as_uint(f);
    u += 0x7fffu + ((u >> 16) & 1u);
    return (u16)(u >> 16);
}

__device__ __forceinline__ void async16(const u16* g, u16* l) {
    __builtin_amdgcn_global_load_lds(
        (const __attribute__((address_space(1))) uint32_t*)g,
        (__attribute__((address_space(3))) uint32_t*)l, 16, 0, 0);
}

// ---------------------------------------------------------------------------
// Kernel 1: pack weights.
// Wbt[o][c][k] (bf16, k-contiguous): for k<1024: j=k>>7,b=k&127,
//   i=(o-7+j)%32, a=7-j  ->  weight[(i*128+b)*8*128 + a*128 + c]
// for k>=1024: r=k-1024 -> L2[(o*128+c)*64 + r]
// L1b: plain f32->bf16 copy of lowrank_first [64][4096].
// ---------------------------------------------------------------------------
__global__ __launch_bounds__(256) void gm_prep(
        const float* __restrict__ W, const float* __restrict__ L1,
        const float* __restrict__ L2,
        u16* __restrict__ Wbt, u16* __restrict__ L1b) {
    int idx = blockIdx.x * 256 + threadIdx.x;
    const int totW = NOB * BSZ * KTOT;          // 4456448
    if (idx < totW) {
        int o   = idx / (BSZ * KTOT);
        int rem = idx % (BSZ * KTOT);
        int c   = rem / KTOT;
        int k   = rem % KTOT;
        float v;
        if (k < 1024) {
            int j = k >> 7, b = k & 127;
            int i = (o + 25 + j) & 31;          // (o-7+j) mod 32
            int a = 7 - j;
            v = W[((i * BSZ + b) * ABI + a) * BSZ + c];
        } else {
            int r = k - 1024;
            v = L2[(o * BSZ + c) * LRK + r];
        }
        Wbt[idx] = f2bf(v);
    } else {
        int i2 = idx - totW;                    // < 64*4096
        L1b[i2] = f2bf(L1[i2]);
    }
}

// ---------------------------------------------------------------------------
// Kernel 2: one pass over x (f32): write x_bf16 and h = x @ L1^T (bf16).
// 512 blocks x 256 thr. Block handles 16 rows; wave w covers K quarter
// [w*1024, w*1024+1024). MFMA 16x16x32, N=64 (4 frags). LDS reduce at end.
// ---------------------------------------------------------------------------
__global__ __launch_bounds__(256) void gm_cast_h(
        const float* __restrict__ x, const u16* __restrict__ L1b,
        u16* __restrict__ xb, u16* __restrict__ hb) {
    __shared__ float red[4][4][256];
    int t = threadIdx.x;
    int w = t >> 6, lane = t & 63;
    int lr = lane & 15, lk = (lane >> 4) << 3;
    int rb = blockIdx.x * 16;
    int row = rb + lr;
    f32x4 acc[4];
#pragma unroll
    for (int ni = 0; ni < 4; ++ni) acc[ni] = (f32x4){0.f, 0.f, 0.f, 0.f};
    const int k_base = w * 1024;
    for (int ks = 0; ks < 32; ++ks) {
        int k0 = k_base + ks * 32 + lk;
        const float* xp = x + (size_t)row * INF + k0;
        f32x4 x0 = *reinterpret_cast<const f32x4*>(xp);
        f32x4 x1 = *reinterpret_cast<const f32x4*>(xp + 4);
        bf16x8 af;
        af[0] = (short)f2bf(x0[0]); af[1] = (short)f2bf(x0[1]);
        af[2] = (short)f2bf(x0[2]); af[3] = (short)f2bf(x0[3]);
        af[4] = (short)f2bf(x1[0]); af[5] = (short)f2bf(x1[1]);
        af[6] = (short)f2bf(x1[2]); af[7] = (short)f2bf(x1[3]);
        *reinterpret_cast<bf16x8*>(xb + (size_t)row * INF + k0) = af;
#pragma unroll
        for (int ni = 0; ni < 4; ++ni) {
            bf16x8 bv = *reinterpret_cast<const bf16x8*>(
                L1b + (size_t)(ni * 16 + lr) * INF + k0);
            acc[ni] = __builtin_amdgcn_mfma_f32_16x16x32_bf16(af, bv, acc[ni], 0, 0, 0);
        }
    }
#pragma unroll
    for (int ni = 0; ni < 4; ++ni)
#pragma unroll
        for (int j = 0; j < 4; ++j) red[w][ni][lane * 4 + j] = acc[ni][j];
    __syncthreads();
    if (t < 64) {
#pragma unroll
        for (int ni = 0; ni < 4; ++ni)
#pragma unroll
            for (int j = 0; j < 4; ++j) {
                float s = red[0][ni][lane * 4 + j] + red[1][ni][lane * 4 + j]
                        + red[2][ni][lane * 4 + j] + red[3][ni][lane * 4 + j];
                int r_ = rb + ((lane >> 4) << 2) + j;   // C/D: row=(lane>>4)*4+j
                int c_ = ni * 16 + (lane & 15);          //      col=lane&15
                hb[(size_t)r_ * LRK + c_] = f2bf(s);
            }
    }
}

// ---------------------------------------------------------------------------
// Kernel 3: main GEMM. grid (64 m-tiles, 32 o). 128x128 tile, BK=64,
// 4 waves (2x2 of 64x64, acc 4x4 frags). global_load_lds width-16 staging.
// A source: x_bf16 band (contiguous mod 4096) for k<1024, h for k>=1024.
// B source: prepacked Wbt[o] ([c][k], k-contiguous -> ds_read_b128 frags).
// ---------------------------------------------------------------------------
__global__ __launch_bounds__(256) void gm_gemm(
        const u16* __restrict__ xb, const u16* __restrict__ hb,
        const u16* __restrict__ Wbt, float* __restrict__ out) {
    __shared__ u16 As[BM * BK];   // [m][k] 128x64
    __shared__ u16 Bs[BN * BK];   // [n][k] 128x64 (B transposed)
    int mt = blockIdx.x;
    int o  = blockIdx.y;
    int t  = threadIdx.x;
    int lane = t & 63, w = t >> 6;
    int wr = w >> 1, wc = w & 1;
    int lr = lane & 15, lk = (lane >> 4) << 3;
    int mbase = mt * BM;
    int srow = t >> 3;            // 0..31
    int scol = (t & 7) << 3;      // 0,8,..,56

    f32x4 acc[4][4];
#pragma unroll
    for (int mi = 0; mi < 4; ++mi)
#pragma unroll
        for (int ni = 0; ni < 4; ++ni) acc[mi][ni] = (f32x4){0.f, 0.f, 0.f, 0.f};

    const u16* wb_o = Wbt + (size_t)o * BSZ * KTOT;

    for (int ks = 0; ks < NKSTEP; ++ks) {
        int k0 = ks * BK;
        __syncthreads();
        // stage A: 128 rows x 64 k
        if (k0 < 1024) {
            int colbase = (((o + 25) * BSZ) + k0) & (INF - 1);  // contiguous within step
            const u16* src = xb + (size_t)mbase * INF + colbase;
#pragma unroll
            for (int q = 0; q < 4; ++q) {
                int r = q * 32 + srow;
                async16(src + (size_t)r * INF + scol, &As[q * 2048 + t * 8]);
            }
        } else {
            const u16* src = hb + (size_t)mbase * LRK;
#pragma unroll
            for (int q = 0; q < 4; ++q) {
                int r = q * 32 + srow;
                async16(src + r * LRK + scol, &As[q * 2048 + t * 8]);
            }
        }
        // stage B: 128 c-rows x 64 k  (row stride KTOT)
        {
            const u16* src = wb_o + k0;
#pragma unroll
            for (int q = 0; q < 4; ++q) {
                int r = q * 32 + srow;
                async16(src + (size_t)r * KTOT + scol, &Bs[q * 2048 + t * 8]);
            }
        }
        __syncthreads();
#pragma unroll
        for (int kk = 0; kk < 2; ++kk) {
            bf16x8 af[4], bv[4];
#pragma unroll
            for (int mi = 0; mi < 4; ++mi)
                af[mi] = *reinterpret_cast<const bf16x8*>(
                    &As[(wr * 64 + mi * 16 + lr) * BK + kk * 32 + lk]);
#pragma unroll
            for (int ni = 0; ni < 4; ++ni)
                bv[ni] = *reinterpret_cast<const bf16x8*>(
                    &Bs[(wc * 64 + ni * 16 + lr) * BK + kk * 32 + lk]);
#pragma unroll
            for (int mi = 0; mi < 4; ++mi)
#pragma unroll
                for (int ni = 0; ni < 4; ++ni)
                    acc[mi][ni] = __builtin_amdgcn_mfma_f32_16x16x32_bf16(
                        af[mi], bv[ni], acc[mi][ni], 0, 0, 0);
        }
    }
    // epilogue: C/D layout col=lane&15, row=(lane>>4)*4+j
    int orow = mbase + wr * 64 + ((lane >> 4) << 2);
    int ocol = o * BSZ + wc * 64 + (lane & 15);
#pragma unroll
    for (int mi = 0; mi < 4; ++mi)
#pragma unroll
        for (int ni = 0; ni < 4; ++ni)
#pragma unroll
            for (int j = 0; j < 4; ++j)
                out[(size_t)(orow + mi * 16 + j) * OUTF + (ocol + ni * 16)] =
                    acc[mi][ni][j];
}

extern "C" void kernel_launch(void* const* d_in, const int* in_sizes, int n_in,
                              void* d_out, int out_size, void* d_ws, size_t ws_size,
                              hipStream_t stream) {
    const float* x  = (const float*)d_in[0];   // [8192][4096]
    const float* W  = (const float*)d_in[1];   // [4096][8][128]
    const float* L1 = (const float*)d_in[2];   // [64][4096]
    const float* L2 = (const float*)d_in[3];   // [4096][64]
    // d_in[4] = forward_indices: fixed circulant (i+a)%32, folded into gm_prep.
    float* out = (float*)d_out;

    char* ws = (char*)d_ws;
    u16* xb  = (u16*)(ws);                       // 8192*4096*2 = 67108864
    u16* hb  = (u16*)(ws + 67108864);            // 8192*64*2   = 1048576
    u16* Wbt = (u16*)(ws + 68157440);            // 32*128*1088*2 = 8912896
    u16* L1b = (u16*)(ws + 77070336);            // 64*4096*2   = 524288

    gm_prep<<<dim3(18432), dim3(256), 0, stream>>>(W, L1, L2, Wbt, L1b);
    gm_cast_h<<<dim3(512), dim3(256), 0, stream>>>(x, L1b, xb, hb);
    gm_gemm<<<dim3(64, 32), dim3(256), 0, stream>>>(xb, hb, Wbt, out);
}